// Round 4
// baseline (251.221 us; speedup 1.0000x reference)
//
#include <hip/hip_runtime.h>

#define EPSF 1e-6f

typedef __bf16 bf16;
typedef bf16 bf16x4 __attribute__((ext_vector_type(4)));
typedef bf16 bf16x8 __attribute__((ext_vector_type(8)));
typedef float f32x4 __attribute__((ext_vector_type(4)));

// N=8, L=S=4096, E=256, H=8, D=32.
// MFMA 16x16x32 bf16 frags: A[m=lane&15][k=(lane>>4)*8+j] (bf16x8),
// B[k=(lane>>4)*8+j][n=lane&15], C/D: col(n)=lane&15, row(m)=(lane>>4)*4+reg.
// Design: barrier-free K-loops with MFMA fragments loaded directly from
// global (X fp32 -> cvt in-lane; W bf16 L2-resident). Kf/Vm stored transposed
// [n][c][s] so kv_outer's A/B frags are s-contiguous bf16x8 reads. KV partials
// per s-chunk (coalesced dwordx4) + reduce kernel -- no atomics anywhere.
// Q-projection is recomputed inside attn (fused), so Qf never hits HBM.

__global__ __launch_bounds__(256) void wconv(
    const float* __restrict__ Wq, const float* __restrict__ Wk,
    const float* __restrict__ Wv, const float* __restrict__ Wm,
    bf16* __restrict__ Wb)
{
    const int b = blockIdx.x, t = threadIdx.x;
    const int m = b >> 6;
    const float* S = (m == 0) ? Wq : (m == 1) ? Wk : (m == 2) ? Wv : Wm;
    const int idx = (b & 63) * 1024 + t * 4;
    float4 v = *(const float4*)(S + idx);
    bf16x4 p = {(bf16)v.x, (bf16)v.y, (bf16)v.z, (bf16)v.w};
    *(bf16x4*)(Wb + (size_t)m * 65536 + idx) = p;
}

// kv_proj: Kf/Vm = act(X @ W^T + b) * mask, stored transposed [n][c][s].
// grid (512, 2): 64-row chunks, z = k/v.
__global__ __launch_bounds__(256) void kv_proj(
    const float* __restrict__ k, const float* __restrict__ v,
    const bf16* __restrict__ Wb,
    const float* __restrict__ bk, const float* __restrict__ bv,
    const int* __restrict__ kv_mask,
    bf16* __restrict__ KfT, bf16* __restrict__ VmT)
{
    const int z  = blockIdx.y;              // 0 = K (elu), 1 = V (no act)
    const int m0 = blockIdx.x * 64;
    const int t = threadIdx.x, lane = t & 63, w = t >> 6;
    const int ln15 = lane & 15, lg = lane >> 4;
    const int wn = w * 64;

    const float* X    = (z == 0) ? k : v;
    const bf16*  W    = Wb + (size_t)(z + 1) * 65536;   // Wk, Wv slots
    const float* bias = (z == 0) ? bk : bv;

    __shared__ bf16 T[64][264];

    f32x4 acc[4][4] = {};
    #pragma unroll 2
    for (int k0 = 0; k0 < 256; k0 += 32) {
        bf16x8 a[4], b[4];
        #pragma unroll
        for (int mi = 0; mi < 4; ++mi) {
            const float* xp = X + (size_t)(m0 + mi * 16 + ln15) * 256 + k0 + lg * 8;
            float4 x0 = *(const float4*)xp;
            float4 x1 = *(const float4*)(xp + 4);
            a[mi] = bf16x8{(bf16)x0.x, (bf16)x0.y, (bf16)x0.z, (bf16)x0.w,
                           (bf16)x1.x, (bf16)x1.y, (bf16)x1.z, (bf16)x1.w};
        }
        #pragma unroll
        for (int ni = 0; ni < 4; ++ni)
            b[ni] = *(const bf16x8*)(W + (size_t)(wn + ni * 16 + ln15) * 256 + k0 + lg * 8);
        #pragma unroll
        for (int mi = 0; mi < 4; ++mi)
            #pragma unroll
            for (int ni = 0; ni < 4; ++ni)
                acc[mi][ni] = __builtin_amdgcn_mfma_f32_16x16x32_bf16(
                    a[mi], b[ni], acc[mi][ni], 0, 0, 0);
    }

    float bb[4];
    #pragma unroll
    for (int ni = 0; ni < 4; ++ni) bb[ni] = bias[wn + ni * 16 + ln15];

    #pragma unroll
    for (int mi = 0; mi < 4; ++mi)
        #pragma unroll
        for (int r = 0; r < 4; ++r) {
            const int row = mi * 16 + lg * 4 + r;
            const float mv = kv_mask[m0 + row] ? 1.f : 0.f;
            #pragma unroll
            for (int ni = 0; ni < 4; ++ni) {
                float x = acc[mi][ni][r] + bb[ni];
                if (z == 0) x = (x > 0.f) ? (x + 1.f) : __expf(x);
                T[row][wn + ni * 16 + ln15] = (bf16)(x * mv);
            }
        }
    __syncthreads();

    bf16* YT = (z == 0) ? KfT : VmT;
    const int n = m0 >> 12, sl = m0 & 4095;
    bf16* dst = YT + ((size_t)n * 256 + t) * 4096 + sl;
    #pragma unroll
    for (int j = 0; j < 8; ++j) {
        bf16x8 vv;
        #pragma unroll
        for (int jj = 0; jj < 8; ++jj) vv[jj] = T[j * 8 + jj][t];
        *(bf16x8*)(dst + j * 8) = vv;
    }
}

// kv_outer: partial KV (D[m=d][n=v]) per 64-row s-chunk via MFMA, frags
// direct from KfT/VmT. No LDS, no barriers, no atomics. grid (64, 8).
__global__ __launch_bounds__(256) void kv_outer(
    const bf16* __restrict__ KfT, const bf16* __restrict__ VmT,
    float* __restrict__ part, float* __restrict__ part_ks)
{
    const int chunk = blockIdx.x, n = blockIdx.y;
    const int s0 = chunk * 64;
    const int t = threadIdx.x, lane = t & 63, w = t >> 6;
    const int ln15 = lane & 15, lg = lane >> 4;

    {   // Ksum partial: col t over 64 s
        const bf16* kp = KfT + ((size_t)n * 256 + t) * 4096 + s0;
        float s = 0.f;
        #pragma unroll
        for (int j = 0; j < 8; ++j) {
            bf16x8 vv = *(const bf16x8*)(kp + j * 8);
            #pragma unroll
            for (int jj = 0; jj < 8; ++jj) s += (float)vv[jj];
        }
        part_ks[((size_t)n * 64 + chunk) * 256 + t] = s;
    }

    #pragma unroll
    for (int hh = 0; hh < 2; ++hh) {
        const int h = w * 2 + hh;
        f32x4 c2[2][2] = {};
        #pragma unroll
        for (int step = 0; step < 2; ++step) {
            const int sb = s0 + step * 32 + lg * 8;
            bf16x8 a[2], b[2];
            #pragma unroll
            for (int mi = 0; mi < 2; ++mi)
                a[mi] = *(const bf16x8*)(KfT + ((size_t)n * 256 + h * 32 + mi * 16 + ln15) * 4096 + sb);
            #pragma unroll
            for (int nj = 0; nj < 2; ++nj)
                b[nj] = *(const bf16x8*)(VmT + ((size_t)n * 256 + h * 32 + nj * 16 + ln15) * 4096 + sb);
            #pragma unroll
            for (int mi = 0; mi < 2; ++mi)
                #pragma unroll
                for (int nj = 0; nj < 2; ++nj)
                    c2[mi][nj] = __builtin_amdgcn_mfma_f32_16x16x32_bf16(
                        a[mi], b[nj], c2[mi][nj], 0, 0, 0);
        }
        float* pb = part + ((size_t)(n * 64 + chunk) * 8 + h) * 1024;
        #pragma unroll
        for (int mi = 0; mi < 2; ++mi)
            #pragma unroll
            for (int nj = 0; nj < 2; ++nj)
                *(f32x4*)(pb + (nj * 16 + ln15) * 32 + mi * 16 + lg * 4) = c2[mi][nj];
    }
}

__global__ __launch_bounds__(256) void kv_reduce(
    const float* __restrict__ part, const float* __restrict__ part_ks,
    bf16* __restrict__ KVb, float* __restrict__ Ksum)
{
    const int nh = blockIdx.x, n = nh >> 3, h = nh & 7;
    const int t = threadIdx.x;
    f32x4 acc = {};
    const float* p = part + ((size_t)n * 512 + h) * 1024 + t * 4;
    for (int c = 0; c < 64; ++c)
        acc += *(const f32x4*)(p + (size_t)c * 8192);
    bf16x4 ob = {(bf16)acc[0], (bf16)acc[1], (bf16)acc[2], (bf16)acc[3]};
    *(bf16x4*)(KVb + (size_t)nh * 1024 + t * 4) = ob;
    if (t < 32) {
        float s = 0.f;
        const float* pk = part_ks + (size_t)n * 16384 + h * 32 + t;
        for (int c = 0; c < 64; ++c) s += pk[c * 256];
        Ksum[n * 256 + h * 32 + t] = s;
    }
}

// attn: fused Q-proj + linear attention + merge GEMM. grid (64, 8).
__global__ __launch_bounds__(256) void attn(
    const float* __restrict__ qin, const bf16* __restrict__ Wb,
    const float* __restrict__ bq, const int* __restrict__ q_mask,
    const bf16* __restrict__ KVb, const float* __restrict__ Ksum,
    float* __restrict__ out)
{
    const int n = blockIdx.y, l0 = blockIdx.x * 64;
    const size_t row0 = (size_t)n * 4096 + l0;
    const int t = threadIdx.x, lane = t & 63, w = t >> 6;
    const int ln15 = lane & 15, lg = lane >> 4;
    const int wn = w * 64;

    const bf16* Wq = Wb;
    const bf16* Wm = Wb + 3 * 65536;

    __shared__ bf16  Qs[64][264];
    __shared__ float KSs[256];
    __shared__ float Dens[64][9];

    KSs[t] = Ksum[n * 256 + t];

    {   // Q-projection (barrier-free core)
        f32x4 acc[4][4] = {};
        #pragma unroll 2
        for (int k0 = 0; k0 < 256; k0 += 32) {
            bf16x8 a[4], b[4];
            #pragma unroll
            for (int mi = 0; mi < 4; ++mi) {
                const float* xp = qin + (row0 + mi * 16 + ln15) * 256 + k0 + lg * 8;
                float4 x0 = *(const float4*)xp;
                float4 x1 = *(const float4*)(xp + 4);
                a[mi] = bf16x8{(bf16)x0.x, (bf16)x0.y, (bf16)x0.z, (bf16)x0.w,
                               (bf16)x1.x, (bf16)x1.y, (bf16)x1.z, (bf16)x1.w};
            }
            #pragma unroll
            for (int ni = 0; ni < 4; ++ni)
                b[ni] = *(const bf16x8*)(Wq + (size_t)(wn + ni * 16 + ln15) * 256 + k0 + lg * 8);
            #pragma unroll
            for (int mi = 0; mi < 4; ++mi)
                #pragma unroll
                for (int ni = 0; ni < 4; ++ni)
                    acc[mi][ni] = __builtin_amdgcn_mfma_f32_16x16x32_bf16(
                        a[mi], b[ni], acc[mi][ni], 0, 0, 0);
        }
        float bb[4];
        #pragma unroll
        for (int ni = 0; ni < 4; ++ni) bb[ni] = bq[wn + ni * 16 + ln15];
        #pragma unroll
        for (int mi = 0; mi < 4; ++mi)
            #pragma unroll
            for (int r = 0; r < 4; ++r) {
                const int row = mi * 16 + lg * 4 + r;
                const float mv = q_mask[row0 + row] ? 1.f : 0.f;
                #pragma unroll
                for (int ni = 0; ni < 4; ++ni) {
                    float x = acc[mi][ni][r] + bb[ni];
                    x = (x > 0.f) ? (x + 1.f) : __expf(x);
                    Qs[row][wn + ni * 16 + ln15] = (bf16)(x * mv);
                }
            }
    }
    __syncthreads();

    #pragma unroll
    for (int i = 0; i < 2; ++i) {   // den[l][h]
        const int idx = t + i * 256;
        const int l = idx & 63, h = idx >> 6;
        float s = 0.f;
        #pragma unroll
        for (int d = 0; d < 32; ++d)
            s += (float)Qs[l][h * 32 + d] * KSs[h * 32 + d];
        Dens[l][h] = s;
    }
    __syncthreads();

    #pragma unroll
    for (int hh = 0; hh < 2; ++hh) {   // num + normalize (wave-disjoint cols)
        const int h = w * 2 + hh;
        const bf16* kvh = KVb + (size_t)(n * 8 + h) * 1024;
        bf16x8 a[2], b[4];
        #pragma unroll
        for (int mi = 0; mi < 2; ++mi)
            a[mi] = *(const bf16x8*)(kvh + (mi * 16 + ln15) * 32 + lg * 8);
        #pragma unroll
        for (int nj = 0; nj < 4; ++nj)
            b[nj] = *(const bf16x8*)&Qs[nj * 16 + ln15][h * 32 + lg * 8];
        f32x4 c[2][4];
        #pragma unroll
        for (int mi = 0; mi < 2; ++mi)
            #pragma unroll
            for (int nj = 0; nj < 4; ++nj) {
                f32x4 z = {};
                c[mi][nj] = __builtin_amdgcn_mfma_f32_16x16x32_bf16(a[mi], b[nj], z, 0, 0, 0);
            }
        #pragma unroll
        for (int nj = 0; nj < 4; ++nj) {
            const int l = nj * 16 + ln15;
            const float rcp = 1.f / (Dens[l][h] + EPSF);
            #pragma unroll
            for (int mi = 0; mi < 2; ++mi) {
                bf16x4 pk;
                #pragma unroll
                for (int r = 0; r < 4; ++r) pk[r] = (bf16)(c[mi][nj][r] * rcp);
                *(bf16x4*)&Qs[l][h * 32 + mi * 16 + lg * 4] = pk;
            }
        }
    }
    __syncthreads();

    {   // merge GEMM: out = Attn @ Wm^T
        f32x4 acc[4][4] = {};
        #pragma unroll 2
        for (int k0 = 0; k0 < 256; k0 += 32) {
            bf16x8 a[4], b[4];
            #pragma unroll
            for (int mi = 0; mi < 4; ++mi)
                a[mi] = *(const bf16x8*)&Qs[mi * 16 + ln15][k0 + lg * 8];
            #pragma unroll
            for (int ni = 0; ni < 4; ++ni)
                b[ni] = *(const bf16x8*)(Wm + (size_t)(wn + ni * 16 + ln15) * 256 + k0 + lg * 8);
            #pragma unroll
            for (int mi = 0; mi < 4; ++mi)
                #pragma unroll
                for (int ni = 0; ni < 4; ++ni)
                    acc[mi][ni] = __builtin_amdgcn_mfma_f32_16x16x32_bf16(
                        a[mi], b[ni], acc[mi][ni], 0, 0, 0);
        }
        #pragma unroll
        for (int ni = 0; ni < 4; ++ni) {
            const int col = wn + ni * 16 + ln15;
            #pragma unroll
            for (int mi = 0; mi < 4; ++mi)
                #pragma unroll
                for (int r = 0; r < 4; ++r)
                    out[(row0 + mi * 16 + lg * 4 + r) * 256 + col] = acc[mi][ni][r];
        }
    }
}

extern "C" void kernel_launch(void* const* d_in, const int* in_sizes, int n_in,
                              void* d_out, int out_size, void* d_ws, size_t ws_size,
                              hipStream_t stream) {
    const float* q      = (const float*)d_in[0];
    const float* k      = (const float*)d_in[1];
    const float* v      = (const float*)d_in[2];
    const int*   q_mask = (const int*)  d_in[3];
    const int*   kv_mask= (const int*)  d_in[4];
    const float* Wq     = (const float*)d_in[5];
    const float* bq     = (const float*)d_in[6];
    const float* Wk     = (const float*)d_in[7];
    const float* bk     = (const float*)d_in[8];
    const float* Wv     = (const float*)d_in[9];
    const float* bv     = (const float*)d_in[10];
    const float* Wm     = (const float*)d_in[11];

    char* ws = (char*)d_ws;
    const size_t SZB = (size_t)8 * 4096 * 256 * sizeof(bf16);     // 16.78 MB
    bf16*  Wb      = (bf16*)ws;                                    // 512 KB (Wq,Wk,Wv,Wm)
    bf16*  KfT     = (bf16*)(ws + 524288);
    bf16*  VmT     = (bf16*)(ws + 524288 + SZB);
    float* part    = (float*)(ws + 524288 + 2 * SZB);              // 16.78 MB
    float* part_ks = (float*)(ws + 524288 + 2 * SZB + 16777216);   // 512 KB
    bf16*  KVb     = (bf16*)(ws + 524288 + 2 * SZB + 16777216 + 524288);   // 128 KB
    float* Ksum    = (float*)(ws + 524288 + 2 * SZB + 16777216 + 524288 + 131072);

    const dim3 blk(256);
    wconv    <<<dim3(256),    blk, 0, stream>>>(Wq, Wk, Wv, Wm, Wb);
    kv_proj  <<<dim3(512, 2), blk, 0, stream>>>(k, v, Wb, bk, bv, kv_mask, KfT, VmT);
    kv_outer <<<dim3(64, 8),  blk, 0, stream>>>(KfT, VmT, part, part_ks);
    kv_reduce<<<dim3(64),     blk, 0, stream>>>(part, part_ks, KVb, Ksum);
    attn     <<<dim3(64, 8),  blk, 0, stream>>>(q, Wb, bq, q_mask, KVb, Ksum, (float*)d_out);
}

// Round 5
// 212.873 us; speedup vs baseline: 1.1801x; 1.1801x over previous
//
#include <hip/hip_runtime.h>

#define EPSF 1e-6f

typedef __bf16 bf16;
typedef bf16 bf16x4 __attribute__((ext_vector_type(4)));
typedef bf16 bf16x8 __attribute__((ext_vector_type(8)));
typedef float f32x4 __attribute__((ext_vector_type(4)));
typedef unsigned int u32;

// N=8, L=S=4096, E=256, H=8, D=32.
// MFMA 16x16x32 bf16 frags: A[m=lane&15][k=(lane>>4)*8+j], B[k][n=lane&15],
// C/D: col=lane&15, row=(lane>>4)*4+reg.
// Core pattern (m97): global_load_lds(16B) staging -> LDS -> frags -> MFMA,
// 2-barrier K-loop, ~4 blocks/CU. LDS can't be padded (wave-uniform dest),
// so bank conflicts are broken by XOR-swizzling the per-lane GLOBAL source
// chunk within each 128B group (coalescing unchanged, ds_reads 2-way = free).

__device__ __forceinline__ void async_ld16(const void* g, void* l) {
    __builtin_amdgcn_global_load_lds(
        (const __attribute__((address_space(1))) u32*)g,
        (__attribute__((address_space(3))) u32*)l, 16, 0, 0);
}

__global__ __launch_bounds__(256) void wconv(
    const float* __restrict__ Wq, const float* __restrict__ Wk,
    const float* __restrict__ Wv, const float* __restrict__ Wm,
    bf16* __restrict__ Wb)
{
    const int b = blockIdx.x, t = threadIdx.x;
    const int m = b >> 6;
    const float* S = (m == 0) ? Wq : (m == 1) ? Wk : (m == 2) ? Wv : Wm;
    const int idx = (b & 63) * 1024 + t * 4;
    float4 v = *(const float4*)(S + idx);
    bf16x4 p = {(bf16)v.x, (bf16)v.y, (bf16)v.z, (bf16)v.w};
    *(bf16x4*)(Wb + (size_t)m * 65536 + idx) = p;
}

// ---------------------------------------------------------------------------
// kvproj: Kf/Vm = act(X @ W^T + b) * mask, stored transposed [n][c][s].
// grid (2 coltiles, 256 rowtiles, 2 z), 256 threads. 128x128 tile, BK=32.
// ---------------------------------------------------------------------------
__global__ __launch_bounds__(256) void kvproj(
    const float* __restrict__ kin, const float* __restrict__ vin,
    const bf16* __restrict__ Wb,
    const float* __restrict__ bk, const float* __restrict__ bv,
    const int* __restrict__ kv_mask,
    bf16* __restrict__ KfT, bf16* __restrict__ VmT)
{
    const int z  = blockIdx.z;
    const int j0 = blockIdx.x * 128;
    const int n  = blockIdx.y >> 5;
    const int s0 = (blockIdx.y & 31) * 128;
    const size_t R0 = (size_t)n * 4096 + s0;

    const int t = threadIdx.x, lane = t & 63, w = t >> 6;
    const int ln15 = lane & 15, lg = lane >> 4;
    const int wm = (w >> 1) * 64, wn = (w & 1) * 64;
    const int wbase = t & ~63;

    const float* X    = z ? vin : kin;
    const bf16*  W    = Wb + (size_t)(z + 1) * 65536;   // Wk, Wv
    const float* bias = z ? bv : bk;

    __shared__ __align__(16) char smem[34816];
    float* Xs = (float*)smem;            // 16384 B: X tile 128x32 f32, swizzled
    bf16*  Ws = (bf16*)(smem + 16384);   //  8192 B: W tile 128x32 bf16, swizzled
    bf16*  T2 = (bf16*)smem;             // epilogue transpose [128 col][136 row]

    f32x4 acc[4][4] = {};

    for (int k0 = 0; k0 < 256; k0 += 32) {
        #pragma unroll
        for (int i = 0; i < 4; ++i) {     // X: 1024 16B-slots
            const int c = i * 256 + t, row = c >> 3, sc = c & 7;
            async_ld16(X + (R0 + row) * 256 + k0 + ((sc ^ (row & 7)) * 4),
                       Xs + (size_t)(i * 256 + wbase) * 4);
        }
        #pragma unroll
        for (int i = 0; i < 2; ++i) {     // W: 512 slots, swizzle over row-pairs
            const int c = i * 256 + t, g = c >> 3, c8 = c & 7;
            const int c8s = c8 ^ (g & 7);
            const int wrow = g * 2 + (c8s >> 2), gch = c8s & 3;
            async_ld16(W + (size_t)(j0 + wrow) * 256 + k0 + gch * 8,
                       Ws + (size_t)(i * 256 + wbase) * 8);
        }
        __syncthreads();

        bf16x8 a[4], b[4];
        #pragma unroll
        for (int mi = 0; mi < 4; ++mi) {
            const int r = wm + mi * 16 + ln15, rb = r & 7;
            f32x4 x0 = *(const f32x4*)&Xs[r * 32 + (((lg * 2)     ^ rb) * 4)];
            f32x4 x1 = *(const f32x4*)&Xs[r * 32 + (((lg * 2 + 1) ^ rb) * 4)];
            a[mi] = bf16x8{(bf16)x0[0], (bf16)x0[1], (bf16)x0[2], (bf16)x0[3],
                           (bf16)x1[0], (bf16)x1[1], (bf16)x1[2], (bf16)x1[3]};
        }
        #pragma unroll
        for (int ni = 0; ni < 4; ++ni) {
            const int wr = wn + ni * 16 + ln15, g = wr >> 1;
            const int c8 = ((wr & 1) * 4 + lg) ^ (g & 7);
            b[ni] = *(const bf16x8*)&Ws[g * 64 + c8 * 8];
        }
        #pragma unroll
        for (int mi = 0; mi < 4; ++mi)
            #pragma unroll
            for (int ni = 0; ni < 4; ++ni)
                acc[mi][ni] = __builtin_amdgcn_mfma_f32_16x16x32_bf16(
                    a[mi], b[ni], acc[mi][ni], 0, 0, 0);
        __syncthreads();
    }

    // epilogue: bias (+elu+1 for z=0), mask, transpose to [col][row] in LDS
    float bb[4];
    #pragma unroll
    for (int ni = 0; ni < 4; ++ni) bb[ni] = bias[j0 + wn + ni * 16 + ln15];
    float mv[4][4];
    #pragma unroll
    for (int mi = 0; mi < 4; ++mi)
        #pragma unroll
        for (int r = 0; r < 4; ++r)
            mv[mi][r] = kv_mask[R0 + wm + mi * 16 + lg * 4 + r] ? 1.f : 0.f;

    #pragma unroll
    for (int ni = 0; ni < 4; ++ni) {
        const int col = wn + ni * 16 + ln15;
        #pragma unroll
        for (int mi = 0; mi < 4; ++mi) {
            const int rowb = wm + mi * 16 + lg * 4;
            bf16x4 pk;
            #pragma unroll
            for (int r = 0; r < 4; ++r) {
                float x = acc[mi][ni][r] + bb[ni];
                if (z == 0) x = (x > 0.f) ? (x + 1.f) : __expf(x);
                pk[r] = (bf16)(x * mv[mi][r]);
            }
            *(bf16x4*)&T2[col * 136 + rowb] = pk;
        }
    }
    __syncthreads();

    // coalesced 128B-per-thread write of the transposed tile
    bf16* YT = z ? VmT : KfT;
    const int cl = t & 127, sh = t >> 7;
    bf16* dst = YT + ((size_t)(n * 256 + j0 + cl)) * 4096 + s0 + sh * 64;
    const bf16* srcp = &T2[cl * 136 + sh * 64];
    #pragma unroll
    for (int i = 0; i < 8; ++i)
        *(bf16x8*)(dst + i * 8) = *(const bf16x8*)(srcp + i * 8);
}

// ---------------------------------------------------------------------------
// kv_outer: partial KV (D[m=d][n=v]) per 64-row s-chunk via MFMA, frags
// direct from KfT/VmT. grid (64, 8). (unchanged from R4 — not the bottleneck)
// ---------------------------------------------------------------------------
__global__ __launch_bounds__(256) void kv_outer(
    const bf16* __restrict__ KfT, const bf16* __restrict__ VmT,
    float* __restrict__ part, float* __restrict__ part_ks)
{
    const int chunk = blockIdx.x, n = blockIdx.y;
    const int s0 = chunk * 64;
    const int t = threadIdx.x, lane = t & 63, w = t >> 6;
    const int ln15 = lane & 15, lg = lane >> 4;

    {   // Ksum partial: col t over 64 s
        const bf16* kp = KfT + ((size_t)n * 256 + t) * 4096 + s0;
        float s = 0.f;
        #pragma unroll
        for (int j = 0; j < 8; ++j) {
            bf16x8 vv = *(const bf16x8*)(kp + j * 8);
            #pragma unroll
            for (int jj = 0; jj < 8; ++jj) s += (float)vv[jj];
        }
        part_ks[((size_t)n * 64 + chunk) * 256 + t] = s;
    }

    #pragma unroll
    for (int hh = 0; hh < 2; ++hh) {
        const int h = w * 2 + hh;
        f32x4 c2[2][2] = {};
        #pragma unroll
        for (int step = 0; step < 2; ++step) {
            const int sb = s0 + step * 32 + lg * 8;
            bf16x8 a[2], b[2];
            #pragma unroll
            for (int mi = 0; mi < 2; ++mi)
                a[mi] = *(const bf16x8*)(KfT + ((size_t)n * 256 + h * 32 + mi * 16 + ln15) * 4096 + sb);
            #pragma unroll
            for (int nj = 0; nj < 2; ++nj)
                b[nj] = *(const bf16x8*)(VmT + ((size_t)n * 256 + h * 32 + nj * 16 + ln15) * 4096 + sb);
            #pragma unroll
            for (int mi = 0; mi < 2; ++mi)
                #pragma unroll
                for (int nj = 0; nj < 2; ++nj)
                    c2[mi][nj] = __builtin_amdgcn_mfma_f32_16x16x32_bf16(
                        a[mi], b[nj], c2[mi][nj], 0, 0, 0);
        }
        float* pb = part + ((size_t)(n * 64 + chunk) * 8 + h) * 1024;
        #pragma unroll
        for (int mi = 0; mi < 2; ++mi)
            #pragma unroll
            for (int nj = 0; nj < 2; ++nj)
                *(f32x4*)(pb + (nj * 16 + ln15) * 32 + mi * 16 + lg * 4) = c2[mi][nj];
    }
}

__global__ __launch_bounds__(256) void kv_reduce(
    const float* __restrict__ part, const float* __restrict__ part_ks,
    bf16* __restrict__ KVb, float* __restrict__ Ksum)
{
    const int nh = blockIdx.x, n = nh >> 3, h = nh & 7;
    const int t = threadIdx.x;
    f32x4 acc = {};
    const float* p = part + ((size_t)n * 512 + h) * 1024 + t * 4;
    for (int c = 0; c < 64; ++c)
        acc += *(const f32x4*)(p + (size_t)c * 8192);
    bf16x4 ob = {(bf16)acc[0], (bf16)acc[1], (bf16)acc[2], (bf16)acc[3]};
    *(bf16x4*)(KVb + (size_t)nh * 1024 + t * 4) = ob;
    if (t < 32) {
        float s = 0.f;
        const float* pk = part_ks + (size_t)n * 16384 + h * 32 + t;
        for (int c = 0; c < 64; ++c) s += pk[c * 256];
        Ksum[n * 256 + h * 32 + t] = s;
    }
}

// ---------------------------------------------------------------------------
// attn: fused Q-proj (staged core) + linear attention + merge GEMM.
// grid (64, 8), 64-row l-tile, 256 threads. Staging LDS aliases Qs.
// ---------------------------------------------------------------------------
__global__ __launch_bounds__(256) void attn(
    const float* __restrict__ qin, const bf16* __restrict__ Wb,
    const float* __restrict__ bq, const int* __restrict__ q_mask,
    const bf16* __restrict__ KVb, const float* __restrict__ Ksum,
    float* __restrict__ out)
{
    const int n = blockIdx.y, l0 = blockIdx.x * 64;
    const size_t R0 = (size_t)n * 4096 + l0;
    const int t = threadIdx.x, lane = t & 63, w = t >> 6;
    const int ln15 = lane & 15, lg = lane >> 4;
    const int wn = w * 64;
    const int wbase = t & ~63;

    const bf16* Wq = Wb;
    const bf16* Wm = Wb + 3 * 65536;

    __shared__ __align__(16) char smem[33792];
    float* Xs  = (float*)smem;           //  8192 B: q tile 64x32 f32 swizzled
    bf16*  Wst = (bf16*)(smem + 8192);   // 16384 B: Wq tile 256x32 swizzled
    bf16 (*Qs)[264] = (bf16(*)[264])smem;
    __shared__ float KSs[256];
    __shared__ float Dens[64][9];

    KSs[t] = Ksum[n * 256 + t];

    {   // ---- Q-projection, staged ----
        f32x4 acc[4][4] = {};
        for (int k0 = 0; k0 < 256; k0 += 32) {
            #pragma unroll
            for (int i = 0; i < 2; ++i) {     // X: 512 slots
                const int c = i * 256 + t, row = c >> 3, sc = c & 7;
                async_ld16(qin + (R0 + row) * 256 + k0 + ((sc ^ (row & 7)) * 4),
                           Xs + (size_t)(i * 256 + wbase) * 4);
            }
            #pragma unroll
            for (int i = 0; i < 4; ++i) {     // W: 1024 slots (all 256 rows)
                const int c = i * 256 + t, g = c >> 3, c8 = c & 7;
                const int c8s = c8 ^ (g & 7);
                const int wrow = g * 2 + (c8s >> 2), gch = c8s & 3;
                async_ld16(Wq + (size_t)wrow * 256 + k0 + gch * 8,
                           Wst + (size_t)(i * 256 + wbase) * 8);
            }
            __syncthreads();

            bf16x8 a[4], b[4];
            #pragma unroll
            for (int mi = 0; mi < 4; ++mi) {
                const int r = mi * 16 + ln15, rb = r & 7;
                f32x4 x0 = *(const f32x4*)&Xs[r * 32 + (((lg * 2)     ^ rb) * 4)];
                f32x4 x1 = *(const f32x4*)&Xs[r * 32 + (((lg * 2 + 1) ^ rb) * 4)];
                a[mi] = bf16x8{(bf16)x0[0], (bf16)x0[1], (bf16)x0[2], (bf16)x0[3],
                               (bf16)x1[0], (bf16)x1[1], (bf16)x1[2], (bf16)x1[3]};
            }
            #pragma unroll
            for (int ni = 0; ni < 4; ++ni) {
                const int wr = wn + ni * 16 + ln15, g = wr >> 1;
                const int c8 = ((wr & 1) * 4 + lg) ^ (g & 7);
                b[ni] = *(const bf16x8*)&Wst[g * 64 + c8 * 8];
            }
            #pragma unroll
            for (int mi = 0; mi < 4; ++mi)
                #pragma unroll
                for (int ni = 0; ni < 4; ++ni)
                    acc[mi][ni] = __builtin_amdgcn_mfma_f32_16x16x32_bf16(
                        a[mi], b[ni], acc[mi][ni], 0, 0, 0);
            __syncthreads();
        }
        float bb[4];
        #pragma unroll
        for (int ni = 0; ni < 4; ++ni) bb[ni] = bq[wn + ni * 16 + ln15];
        float mv[4][4];
        #pragma unroll
        for (int mi = 0; mi < 4; ++mi)
            #pragma unroll
            for (int r = 0; r < 4; ++r)
                mv[mi][r] = q_mask[R0 + mi * 16 + lg * 4 + r] ? 1.f : 0.f;
        #pragma unroll
        for (int mi = 0; mi < 4; ++mi)
            #pragma unroll
            for (int r = 0; r < 4; ++r) {
                const int row = mi * 16 + lg * 4 + r;
                #pragma unroll
                for (int ni = 0; ni < 4; ++ni) {
                    float x = acc[mi][ni][r] + bb[ni];
                    x = (x > 0.f) ? (x + 1.f) : __expf(x);
                    Qs[row][wn + ni * 16 + ln15] = (bf16)(x * mv[mi][r]);
                }
            }
    }
    __syncthreads();

    #pragma unroll
    for (int i = 0; i < 2; ++i) {   // den[l][h]
        const int idx = t + i * 256;
        const int l = idx & 63, h = idx >> 6;
        float s = 0.f;
        #pragma unroll
        for (int d = 0; d < 32; ++d)
            s += (float)Qs[l][h * 32 + d] * KSs[h * 32 + d];
        Dens[l][h] = s;
    }
    __syncthreads();

    #pragma unroll
    for (int hh = 0; hh < 2; ++hh) {   // num + normalize (wave-disjoint cols)
        const int h = w * 2 + hh;
        const bf16* kvh = KVb + (size_t)(n * 8 + h) * 1024;
        bf16x8 a[2], b[4];
        #pragma unroll
        for (int mi = 0; mi < 2; ++mi)
            a[mi] = *(const bf16x8*)(kvh + (mi * 16 + ln15) * 32 + lg * 8);
        #pragma unroll
        for (int nj = 0; nj < 4; ++nj)
            b[nj] = *(const bf16x8*)&Qs[nj * 16 + ln15][h * 32 + lg * 8];
        f32x4 c[2][4];
        #pragma unroll
        for (int mi = 0; mi < 2; ++mi)
            #pragma unroll
            for (int nj = 0; nj < 4; ++nj) {
                f32x4 zz = {};
                c[mi][nj] = __builtin_amdgcn_mfma_f32_16x16x32_bf16(a[mi], b[nj], zz, 0, 0, 0);
            }
        #pragma unroll
        for (int nj = 0; nj < 4; ++nj) {
            const int l = nj * 16 + ln15;
            const float rcp = 1.f / (Dens[l][h] + EPSF);
            #pragma unroll
            for (int mi = 0; mi < 2; ++mi) {
                bf16x4 pk;
                #pragma unroll
                for (int r = 0; r < 4; ++r) pk[r] = (bf16)(c[mi][nj][r] * rcp);
                *(bf16x4*)&Qs[l][h * 32 + mi * 16 + lg * 4] = pk;
            }
        }
    }
    __syncthreads();

    {   // merge GEMM: out = Attn @ Wm^T (A from LDS, B from L2-hot Wm)
        f32x4 acc[4][4] = {};
        #pragma unroll 2
        for (int k0 = 0; k0 < 256; k0 += 32) {
            bf16x8 a[4], b[4];
            #pragma unroll
            for (int mi = 0; mi < 4; ++mi)
                a[mi] = *(const bf16x8*)&Qs[mi * 16 + ln15][k0 + lg * 8];
            #pragma unroll
            for (int ni = 0; ni < 4; ++ni)
                b[ni] = *(const bf16x8*)(Wm + (size_t)(wn + ni * 16 + ln15) * 256 + k0 + lg * 8);
            #pragma unroll
            for (int mi = 0; mi < 4; ++mi)
                #pragma unroll
                for (int ni = 0; ni < 4; ++ni)
                    acc[mi][ni] = __builtin_amdgcn_mfma_f32_16x16x32_bf16(
                        a[mi], b[ni], acc[mi][ni], 0, 0, 0);
        }
        #pragma unroll
        for (int ni = 0; ni < 4; ++ni) {
            const int col = wn + ni * 16 + ln15;
            #pragma unroll
            for (int mi = 0; mi < 4; ++mi)
                #pragma unroll
                for (int r = 0; r < 4; ++r)
                    out[(R0 + mi * 16 + lg * 4 + r) * 256 + col] = acc[mi][ni][r];
        }
    }
}

extern "C" void kernel_launch(void* const* d_in, const int* in_sizes, int n_in,
                              void* d_out, int out_size, void* d_ws, size_t ws_size,
                              hipStream_t stream) {
    const float* q      = (const float*)d_in[0];
    const float* k      = (const float*)d_in[1];
    const float* v      = (const float*)d_in[2];
    const int*   q_mask = (const int*)  d_in[3];
    const int*   kv_mask= (const int*)  d_in[4];
    const float* Wq     = (const float*)d_in[5];
    const float* bq     = (const float*)d_in[6];
    const float* Wk     = (const float*)d_in[7];
    const float* bk     = (const float*)d_in[8];
    const float* Wv     = (const float*)d_in[9];
    const float* bv     = (const float*)d_in[10];
    const float* Wm     = (const float*)d_in[11];

    char* ws = (char*)d_ws;
    const size_t SZB = (size_t)8 * 4096 * 256 * sizeof(bf16);     // 16.78 MB
    bf16*  Wb      = (bf16*)ws;                                    // 512 KB
    bf16*  KfT     = (bf16*)(ws + 524288);
    bf16*  VmT     = (bf16*)(ws + 524288 + SZB);
    float* part    = (float*)(ws + 524288 + 2 * SZB);              // 16.78 MB
    float* part_ks = (float*)(ws + 524288 + 2 * SZB + 16777216);   // 512 KB
    bf16*  KVb     = (bf16*)(ws + 524288 + 2 * SZB + 16777216 + 524288);   // 128 KB
    float* Ksum    = (float*)(ws + 524288 + 2 * SZB + 16777216 + 524288 + 131072);

    const dim3 blk(256);
    wconv    <<<dim3(256),      blk, 0, stream>>>(Wq, Wk, Wv, Wm, Wb);
    kvproj   <<<dim3(2, 256, 2),blk, 0, stream>>>(k, v, Wb, bk, bv, kv_mask, KfT, VmT);
    kv_outer <<<dim3(64, 8),    blk, 0, stream>>>(KfT, VmT, part, part_ks);
    kv_reduce<<<dim3(64),       blk, 0, stream>>>(part, part_ks, KVb, Ksum);
    attn     <<<dim3(64, 8),    blk, 0, stream>>>(q, Wb, bq, q_mask, KVb, Ksum, (float*)d_out);
}